// Round 19
// baseline (181.094 us; speedup 1.0000x reference)
//
#include <hip/hip_runtime.h>
#include <cmath>

// Problem constants
#define NG    128       // graphs
#define NPER  512       // nodes per graph (layer 1)
#define NTOT  65536     // total nodes
#define NEDGE 1048576   // total edges
#define EPG   8192      // edges per graph
#define DD    128
#define K1    256       // kept nodes per graph after pool1
#define K2    128       // kept nodes per graph after pool2
#define SLOTS 56        // fixed edge-bucket slots per node (max degree ~40)

typedef float f32x4 __attribute__((ext_vector_type(4)));
typedef short short8 __attribute__((ext_vector_type(8)));

// 16B-chunk swizzle within a 64B row (shorts offset): conflict-free LDS
__device__ __forceinline__ int SW(int row, int c) { return (c ^ ((row >> 1) & 3)) * 8; }

__device__ __forceinline__ void bsplit(float v, short& h, short& l) {
  unsigned u = __builtin_bit_cast(unsigned, v);
  h = (short)(u >> 16);
  float lf = v - __builtin_bit_cast(float, u & 0xFFFF0000u);
  l = (short)(__builtin_bit_cast(unsigned, lf) >> 16);
}

// async global -> LDS, 16 bytes per lane (lane-linear dest)
__device__ __forceinline__ void gload16(const void* g, void* l) {
  __builtin_amdgcn_global_load_lds(
      (const __attribute__((address_space(1))) unsigned int*)g,
      (__attribute__((address_space(3))) unsigned int*)l, 16, 0, 0);
}

// ---------------------------------------------------------------------------
// Prep: split weights into bf16 hi/lo, MFMA-fragment-ordered layout.
// Also zero cnt and compute ||pool1_w||, ||pool2_w|| into norms[0..1].
// ---------------------------------------------------------------------------
__global__ __launch_bounds__(256) void build_wt_all(
    const float* __restrict__ W1, const float* __restrict__ W2,
    const float* __restrict__ W3, const float* __restrict__ W4,
    const float* __restrict__ pw1, const float* __restrict__ pw2,
    short* __restrict__ h1, short* __restrict__ l1,
    short* __restrict__ h2, short* __restrict__ l2,
    int* __restrict__ cnt, float* __restrict__ norms) {
  const int n = blockIdx.x, k = threadIdx.x;   // n: out-col 0..255, k: 0..255
  cnt[n * 256 + k] = 0;
  const int t = k >> 5, k5 = k & 31, cq = k5 >> 3, i = k5 & 7;
  const int nhalf = n >> 7, nf = (n >> 4) & 7, l = n & 15;
  const int off = ((((t * 2 + nhalf) * 8 + nf) * 4 + cq) * 16 + l) * 8 + i;
  {
    float w = (nhalf == 0) ? W1[k * 128 + n] : W2[k * 128 + (n - 128)];
    short h, lo; bsplit(w, h, lo);
    h1[off] = h; l1[off] = lo;
  }
  if (k < 128) {
    float w = (nhalf == 0) ? W3[k * 128 + n] : W4[k * 128 + (n - 128)];
    short h, lo; bsplit(w, h, lo);
    h2[off] = h; l2[off] = lo;
  }
  if (n == 0) {
    const int lane = k & 63, wid = k >> 6;
    if (wid < 2 && lane < 32) {
      const float* pw = (wid == 0) ? pw1 : pw2;
      f32x4 wv = *(const f32x4*)&pw[lane * 4];
      float nr = wv[0]*wv[0] + wv[1]*wv[1] + wv[2]*wv[2] + wv[3]*wv[3];
#pragma unroll
      for (int m = 16; m >= 1; m >>= 1) nr += __shfl_xor(nr, m);
      if (lane == 0) norms[wid] = sqrtf(nr);
    }
  }
}

// ---------------------------------------------------------------------------
// Split-bf16 MFMA dual GEMM + edge-bucket fill with decoupled atomics.
// A [M,K] f32 -> C1 = A@W1, C2 = A@W2 (both f32). Tile MT x 256N, 4 waves.
// W double-buffered in LDS via global_load_lds, staged BEFORE compute.
// Fill: prologue loads 8 edges/thread and issues all 8 atomicAdds as
// INDEPENDENT chains (prologue barrier drains them once); the K-loop does
// only fire-and-forget stores (EPT per tile), completion covered by MFMA.
// Grid must be 512 blocks. eid must NOT alias any buffer this kernel touches.
// ---------------------------------------------------------------------------
template<int K, int MT, bool FILL2>
__global__ __launch_bounds__(256, 2) void gemm_fill(
    const float* __restrict__ A,
    const short* __restrict__ wth, const short* __restrict__ wtl,
    float* __restrict__ C1, float* __restrict__ C2,
    const int* __restrict__ esrc, const int* __restrict__ edst,
    const int* __restrict__ map, int* __restrict__ cnt, int* __restrict__ eid) {
  constexpr int MF = MT / 32;          // 16-row frags per wave
  constexpr int NP = MT / 32;          // float4s staged per thread
  constexpr int NT = K / 32;
  constexpr int EPT = 8 / NT;          // fill stores per K-tile (1 or 2)
  __shared__ short Ah[MT * 32], Al[MT * 32];
  __shared__ short WHL[2][16384];      // [buf][hi 8192 | lo 8192]
  const int tid = threadIdx.x, lane = tid & 63, wid = tid >> 6;

  const int wm = (wid >> 1) * (MT / 2);
  const int nhalf = wid & 1;           // 0 -> C1, 1 -> C2
  const size_t row0 = (size_t)blockIdx.x * MT;
  const int l15 = lane & 15, cq = lane >> 4;
  const int wfrag = nhalf * 4096 + cq * 128 + l15 * 8;   // B-frag base (shorts)
  const int ar  = (MT == 128) ? (tid >> 1) : (tid >> 2);
  const int cb0 = (MT == 128) ? ((tid & 1) * 2) : (tid & 3);
  const float* ap = A + (row0 + ar) * K + cb0 * 8;

  float4 pa[NP];
  auto load_a = [&](int t) {
    const float4* p = (const float4*)(ap + t * 32);
#pragma unroll
    for (int i = 0; i < NP; ++i) pa[i] = p[i];
  };
  auto store_a = [&]() {
#pragma unroll
    for (int c = 0; c < NP / 2; ++c) {   // per pair of float4s = 8 floats
      float ff[8] = {pa[2*c].x, pa[2*c].y, pa[2*c].z, pa[2*c].w,
                     pa[2*c+1].x, pa[2*c+1].y, pa[2*c+1].z, pa[2*c+1].w};
      short8 hv, lv;
#pragma unroll
      for (int i = 0; i < 8; ++i) {
        short hh, ll; bsplit(ff[i], hh, ll); hv[i] = hh; lv[i] = ll;
      }
      *(short8*)&Ah[ar * 32 + SW(ar, cb0 + c)] = hv;
      *(short8*)&Al[ar * 32 + SW(ar, cb0 + c)] = lv;
    }
  };
  auto stage_w = [&](int t, int b) {
#pragma unroll
    for (int j = 0; j < 8; ++j) {
      int c = wid * 8 + j;
      const short* gs = (c < 16) ? wth + (size_t)t * 8192 + c * 512 + lane * 8
                                 : wtl + (size_t)t * 8192 + (c - 16) * 512 + lane * 8;
      gload16(gs, &WHL[b][c * 512 + lane * 8]);
    }
  };

  f32x4 acc[MF][8];
#pragma unroll
  for (int mf = 0; mf < MF; ++mf)
#pragma unroll
    for (int nf = 0; nf < 8; ++nf) acc[mf][nf] = (f32x4){0.f, 0.f, 0.f, 0.f};

  // prologue: GEMM staging + edge loads + ALL atomics (independent chains)
  load_a(0);
  stage_w(0, 0);
  int fsrc[8], fdst[8], fpos[8];
#pragma unroll
  for (int i = 0; i < 8; ++i) {
    int e = blockIdx.x * 2048 + i * 256 + tid;
    if (!FILL2) {
      fsrc[i] = esrc[e];
      fdst[i] = edst[e];
    } else {
      fsrc[i] = map[esrc[e]];
      fdst[i] = map[edst[e]];
    }
  }
#pragma unroll
  for (int i = 0; i < 8; ++i) {
    if (!FILL2 || (fsrc[i] | fdst[i]) >= 0)
      fpos[i] = atomicAdd(&cnt[fdst[i]], 1);
    else
      fpos[i] = -1;
  }
  store_a();
  __syncthreads();                    // drains W(0), A(0) writes, all atomics
  int cur = 0;

  for (int t = 0; t < NT; ++t) {
    if (t + 1 < NT) {
      load_a(t + 1);                  // global -> regs, lands during compute
      stage_w(t + 1, cur ^ 1);        // async -> other W buffer
    }
    // fill stores: no dependencies; completion hidden under MFMA cluster
#pragma unroll
    for (int q = 0; q < EPT; ++q) {
      int i = t * EPT + q;
      if (fpos[i] >= 0)
        eid[fdst[i] * SLOTS + fpos[i]] = fsrc[i];
    }
    // compute tile t
    short8 ah[MF], al[MF];
#pragma unroll
    for (int mf = 0; mf < MF; ++mf) {
      int r = wm + mf * 16 + l15;
      ah[mf] = *(const short8*)&Ah[r * 32 + SW(r, cq)];
      al[mf] = *(const short8*)&Al[r * 32 + SW(r, cq)];
    }
#pragma unroll
    for (int nf = 0; nf < 8; ++nf) {
      short8 bh = *(const short8*)&WHL[cur][nf * 512 + wfrag];
      short8 bl = *(const short8*)&WHL[cur][8192 + nf * 512 + wfrag];
#pragma unroll
      for (int mf = 0; mf < MF; ++mf) {
        acc[mf][nf] = __builtin_amdgcn_mfma_f32_16x16x32_bf16(ah[mf], bh, acc[mf][nf], 0, 0, 0);
        acc[mf][nf] = __builtin_amdgcn_mfma_f32_16x16x32_bf16(ah[mf], bl, acc[mf][nf], 0, 0, 0);
        acc[mf][nf] = __builtin_amdgcn_mfma_f32_16x16x32_bf16(al[mf], bh, acc[mf][nf], 0, 0, 0);
      }
    }
    if (t + 1 < NT) {
      __syncthreads();                // ends reads of A(t)/W(t)
      store_a();                      // A(t+1) -> LDS (single buffer, safe now)
      __syncthreads();                // ds_writes visible
      cur ^= 1;
    }
  }

  float* Cb = nhalf ? C2 : C1;
#pragma unroll
  for (int mf = 0; mf < MF; ++mf) {
    size_t rbase = row0 + wm + mf * 16 + cq * 4;
#pragma unroll
    for (int nf = 0; nf < 8; ++nf) {
      int c = nf * 16 + l15;
#pragma unroll
      for (int r = 0; r < 4; ++r)
        Cb[(rbase + r) * 128 + c] = acc[mf][nf][r];
    }
  }
}

// ---------------------------------------------------------------------------
// Gather aggregation: ONE WAVE PER BLOCK (64 threads) -> zero intra-block
// wave imbalance. Whole bucket in one coalesced load; 4 chains, 2 edges per
// f32x4 load; ||w|| precomputed. Fused TopK score. XCD-swizzled blocks.
// ---------------------------------------------------------------------------
template<int CPX>
__global__ __launch_bounds__(64) void agg_gather(
    const float* __restrict__ xr, const float* __restrict__ xo,
    const float* __restrict__ brel, const int* __restrict__ cnt,
    const int* __restrict__ eid, const float* __restrict__ pw,
    const float* __restrict__ wnorm_p,
    float* __restrict__ hout, float* __restrict__ score) {
  const int bid = blockIdx.x;
  const int node = (bid & 7) * CPX + (bid >> 3);   // XCD swizzle
  const int lane = threadIdx.x;
  const int dg = cnt[node];           // wave-uniform
  const int base = node * SLOTS;
  const int half = lane >> 5, l32 = lane & 31;
  const int eall = eid[base + lane];  // whole bucket, one coalesced load
  const float wnorm = wnorm_p[0];     // uniform scalar
  f32x4 a0 = {0.f, 0.f, 0.f, 0.f}, a1 = a0, a2 = a0, a3 = a0;
  int j = 0;
  for (; j + 8 <= dg; j += 8) {       // uniform branch
    int e0 = __shfl(eall, j + 0 + half);
    int e1 = __shfl(eall, j + 2 + half);
    int e2 = __shfl(eall, j + 4 + half);
    int e3 = __shfl(eall, j + 6 + half);
    a0 += *(const f32x4*)&xr[(size_t)e0 * 128 + l32 * 4];
    a1 += *(const f32x4*)&xr[(size_t)e1 * 128 + l32 * 4];
    a2 += *(const f32x4*)&xr[(size_t)e2 * 128 + l32 * 4];
    a3 += *(const f32x4*)&xr[(size_t)e3 * 128 + l32 * 4];
  }
  if (j + 4 <= dg) {
    int e0 = __shfl(eall, j + 0 + half);
    int e1 = __shfl(eall, j + 2 + half);
    a0 += *(const f32x4*)&xr[(size_t)e0 * 128 + l32 * 4];
    a1 += *(const f32x4*)&xr[(size_t)e1 * 128 + l32 * 4];
    j += 4;
  }
  if (j + 2 <= dg) {
    int e0 = __shfl(eall, j + half);
    a2 += *(const f32x4*)&xr[(size_t)e0 * 128 + l32 * 4];
    j += 2;
  }
  {
    int e0 = __shfl(eall, j);
    if (j < dg && half == 0)
      a3 += *(const f32x4*)&xr[(size_t)e0 * 128 + l32 * 4];
  }
  f32x4 s = a0 + a1 + a2 + a3;
  s[0] += __shfl_xor(s[0], 32);
  s[1] += __shfl_xor(s[1], 32);
  s[2] += __shfl_xor(s[2], 32);
  s[3] += __shfl_xor(s[3], 32);
  float dot = 0.f;
  if (half == 0) {
    const f32x4 wv = *(const f32x4*)&pw[l32 * 4];
    f32x4 b = *(const f32x4*)&brel[l32 * 4];
    f32x4 o = *(const f32x4*)&xo[(size_t)node * 128 + l32 * 4];
    f32x4 h;
#pragma unroll
    for (int i = 0; i < 4; ++i) {
      h[i] = fmaxf(s[i] + b[i] + o[i], 0.f);
      dot += h[i] * wv[i];
    }
    *(f32x4*)&hout[(size_t)node * 128 + l32 * 4] = h;
  }
#pragma unroll
  for (int m = 16; m >= 1; m >>= 1) dot += __shfl_xor(dot, m);
  if (lane == 0)
    score[node] = 1.f / (1.f + expf(-dot / wnorm));
}

// ---------------------------------------------------------------------------
// TopK pool 1 (512 -> 256 per graph): scores precomputed by agg_gather.
// Also zeroes cnt for layer 2.
// ---------------------------------------------------------------------------
__global__ __launch_bounds__(512) void topk1_kernel(
    const float* __restrict__ h1, const float* __restrict__ score_in,
    float* __restrict__ xnew, int* __restrict__ map, int* __restrict__ cnt,
    float* __restrict__ x1p, float* __restrict__ score_out) {
  const int g = blockIdx.x, tid = threadIdx.x;
  __shared__ float sc[NPER];
  __shared__ int si[NPER];
  __shared__ float xn[K1 * 128];
  __shared__ float redm[4 * 128];
  __shared__ float reds[4 * 128];
  {
    int gt = g * 512 + tid;
    if (gt < NG * K1) cnt[gt] = 0;   // zero layer-2 buckets
  }
  sc[tid] = score_in[g * NPER + tid];
  si[tid] = tid;

  // bitonic sort, descending score, ties -> lower index first (lax.top_k)
  for (int k = 2; k <= NPER; k <<= 1) {
    for (int j = k >> 1; j > 0; j >>= 1) {
      __syncthreads();
      int p = tid ^ j;
      if (p > tid) {
        float sa = sc[tid], sb = sc[p];
        int ia = si[tid], ib = si[p];
        bool before = (sb > sa) || (sb == sa && ib < ia);
        if (before == ((tid & k) == 0)) {
          sc[tid] = sb; sc[p] = sa; si[tid] = ib; si[p] = ia;
        }
      }
    }
  }
  __syncthreads();

  map[g * NPER + tid] = -1;
  if (tid < K1) score_out[g * K1 + tid] = sc[tid];
  __syncthreads();
  if (tid < K1) map[g * NPER + si[tid]] = g * K1 + tid;

  const int wave = tid >> 6, lane = tid & 63;
  for (int j = wave; j < K1; j += 8) {
    int idx = si[j];
    float s2 = sc[j];
    float2 v = *(const float2*)&h1[(size_t)(g * NPER + idx) * 128 + lane * 2];
    float2 o;
    o.x = v.x * s2;
    o.y = v.y * s2;
    *(float2*)&xnew[(size_t)(g * K1 + j) * 128 + lane * 2] = o;
    xn[j * 128 + lane * 2] = o.x;
    xn[j * 128 + lane * 2 + 1] = o.y;
  }
  __syncthreads();

  const int c = tid & 127, grp = tid >> 7;   // 4 groups
  float mx = -1e30f, sm = 0.f;
  for (int r = grp; r < K1; r += 4) {
    float v = xn[r * 128 + c];
    mx = fmaxf(mx, v);
    sm += v;
  }
  redm[grp * 128 + c] = mx;
  reds[grp * 128 + c] = sm;
  __syncthreads();
  if (tid < 128) {
    float m = fmaxf(fmaxf(redm[c], redm[128 + c]), fmaxf(redm[256 + c], redm[384 + c]));
    float su = reds[c] + reds[128 + c] + reds[256 + c] + reds[384 + c];
    x1p[g * 256 + tid] = m;
    x1p[g * 256 + 128 + tid] = su * (1.f / 256.f);
  }
}

// ---------------------------------------------------------------------------
// TopK pool 2 (256 -> 128, scores precomputed) fused with classifier head.
// ---------------------------------------------------------------------------
__global__ __launch_bounds__(256) void topk2_head_kernel(
    const float* __restrict__ h2, const float* __restrict__ score_in,
    const float* __restrict__ x1p,
    const float* __restrict__ lin1_w, const float* __restrict__ lin1_b,
    const float* __restrict__ bng, const float* __restrict__ bnb,
    const float* __restrict__ bnm, const float* __restrict__ bnv,
    const float* __restrict__ lin2_w, const float* __restrict__ lin2_b,
    const float* __restrict__ pool1_w, float* __restrict__ out) {
  const int g = blockIdx.x, tid = threadIdx.x;
  __shared__ float sc[K1];
  __shared__ int si[K1];
  __shared__ float xn[K2 * 128];
  __shared__ float redm[2 * 128];
  __shared__ float reds[2 * 128];
  __shared__ float ge[256];
  __shared__ float zz[128];
  __shared__ float lg[16];
  sc[tid] = score_in[g * K1 + tid];
  si[tid] = tid;
  for (int k = 2; k <= K1; k <<= 1) {
    for (int j = k >> 1; j > 0; j >>= 1) {
      __syncthreads();
      int p = tid ^ j;
      if (p > tid) {
        float sa = sc[tid], sb = sc[p];
        int ia = si[tid], ib = si[p];
        bool before = (sb > sa) || (sb == sa && ib < ia);
        if (before == ((tid & k) == 0)) {
          sc[tid] = sb; sc[p] = sa; si[tid] = ib; si[p] = ia;
        }
      }
    }
  }
  __syncthreads();
  const int wave = tid >> 6, lane = tid & 63;  // 4 waves
  for (int j = wave; j < K2; j += 4) {
    int idx = si[j];
    float s2 = sc[j];
    float2 v = *(const float2*)&h2[(size_t)(g * K1 + idx) * 128 + lane * 2];
    xn[j * 128 + lane * 2] = v.x * s2;
    xn[j * 128 + lane * 2 + 1] = v.y * s2;
  }
  __syncthreads();
  const int c = tid & 127, grp = tid >> 7;  // 2 groups
  float mx = -1e30f, sm = 0.f;
  for (int r = grp; r < K2; r += 2) {
    float v = xn[r * 128 + c];
    mx = fmaxf(mx, v);
    sm += v;
  }
  redm[grp * 128 + c] = mx;
  reds[grp * 128 + c] = sm;
  __syncthreads();
  // ---- head ----
  if (tid < 128) {
    float m = fmaxf(redm[c], redm[128 + c]);
    float su = (reds[c] + reds[128 + c]) * (1.f / 128.f);
    float v1 = x1p[g * 256 + tid] + m;
    float v2 = x1p[g * 256 + 128 + tid] + su;
    ge[tid] = v1;
    ge[128 + tid] = v2;
    out[2048 + g * 256 + tid] = v1;          // g_emb output
    out[2048 + g * 256 + 128 + tid] = v2;
  }
  __syncthreads();
  if (tid < 128) {
    float a = lin1_b[tid];
    for (int k = 0; k < 256; ++k) a += ge[k] * lin1_w[k * 128 + tid];
    a = fmaxf(a, 0.f);
    a = (a - bnm[tid]) * bng[tid] / sqrtf(bnv[tid] + 1e-5f) + bnb[tid];
    zz[tid] = a;
  }
  __syncthreads();
  if (tid < 16) {
    float o = lin2_b[tid];
    for (int k = 0; k < 128; ++k) o += zz[k] * lin2_w[k * 16 + tid];
    lg[tid] = o;
  }
  __syncthreads();
  if (tid < 16) {
    float m = lg[0];
    for (int j = 1; j < 16; ++j) m = fmaxf(m, lg[j]);
    float ssum = 0.f;
    for (int j = 0; j < 16; ++j) ssum += expf(lg[j] - m);
    out[g * 16 + tid] = lg[tid] - m - logf(ssum);
  }
  if (g == 0 && tid < 128) out[34816 + tid] = pool1_w[tid];  // pool1_w output
}

// ---------------------------------------------------------------------------
extern "C" void kernel_launch(void* const* d_in, const int* in_sizes, int n_in,
                              void* d_out, int out_size, void* d_ws, size_t ws_size,
                              hipStream_t stream) {
  const float* x       = (const float*)d_in[0];
  const int*   ei      = (const int*)d_in[1];
  const float* w_rel1  = (const float*)d_in[3];
  const float* b_rel1  = (const float*)d_in[4];
  const float* w_root1 = (const float*)d_in[5];
  const float* pool1_w = (const float*)d_in[6];
  const float* w_rel2  = (const float*)d_in[7];
  const float* b_rel2  = (const float*)d_in[8];
  const float* w_root2 = (const float*)d_in[9];
  const float* pool2_w = (const float*)d_in[10];
  const float* lin1_w  = (const float*)d_in[11];
  const float* lin1_b  = (const float*)d_in[12];
  const float* bng     = (const float*)d_in[13];
  const float* bnb     = (const float*)d_in[14];
  const float* bnm     = (const float*)d_in[15];
  const float* bnv     = (const float*)d_in[16];
  const float* lin2_w  = (const float*)d_in[17];
  const float* lin2_b  = (const float*)d_in[18];
  const int* src = ei;
  const int* dst = ei + NEDGE;

  char* ws = (char*)d_ws;
  // Memory map (bytes):
  //  [0,16M)      xr2 (layer2)        ; layer1: xr1 lower half
  //  [0,32M)      xr1 [65536][128]
  //  [16M,32M)    xo2 (layer2)
  //  [32M,48M)    xoh1/h1 lower half  ; layer2: h2
  //  [48M,~55.3M) eid2 (dead h1 upper half during gemm2/agg2)
  //  [32M,64M)    xoh1/h1 (layer1)
  //  [64M,~78.7M) eid1 (during gemm1/agg1) -> xnew [64M,80M) after topk1
  //  [80M,..)     map, cnt, x1p, sc1, sc2, wth/wtl, norms
  float* xr1  = (float*)(ws + 0);
  float* xoh1 = (float*)(ws + 33554432UL);
  float* xnew = (float*)(ws + 67108864UL);
  int*   eid1 = (int*)  (ws + 67108864UL);
  int*   eid2 = (int*)  (ws + 50331648UL);
  int*   map  = (int*)  (ws + 83886080UL);
  int*   cnt  = (int*)  (ws + 84148224UL);
  float* x1p  = (float*)(ws + 84410368UL);
  float* sc1  = (float*)(ws + 84541440UL);
  float* sc2  = (float*)(ws + 84803584UL);
  short* wth1 = (short*)(ws + 84934656UL);
  short* wtl1 = (short*)(ws + 85065728UL);
  short* wth2 = (short*)(ws + 85196800UL);
  short* wtl2 = (short*)(ws + 85262336UL);
  float* norms = (float*)(ws + 85327872UL);
  float* xr2  = (float*)(ws + 0);
  float* xo2  = (float*)(ws + 16777216UL);
  float* h2   = xoh1;
  float* out  = (float*)d_out;

  // ---- Layer 1 ----
  build_wt_all<<<dim3(256), dim3(256), 0, stream>>>(
      w_rel1, w_root1, w_rel2, w_root2, pool1_w, pool2_w,
      wth1, wtl1, wth2, wtl2, cnt, norms);
  gemm_fill<256, 128, false><<<dim3(512), dim3(256), 0, stream>>>(
      x, wth1, wtl1, xr1, xoh1, src, dst, nullptr, cnt, eid1);
  agg_gather<8192><<<dim3(NTOT), dim3(64), 0, stream>>>(
      xr1, xoh1, b_rel1, cnt, eid1, pool1_w, norms, xoh1, sc1);
  topk1_kernel<<<dim3(NG), dim3(512), 0, stream>>>(xoh1, sc1, xnew, map, cnt, x1p, out + 34944);

  // ---- Layer 2 ----
  gemm_fill<128, 64, true><<<dim3(512), dim3(256), 0, stream>>>(
      xnew, wth2, wtl2, xr2, xo2, src, dst, map, cnt, eid2);
  agg_gather<4096><<<dim3(NG * K1), dim3(64), 0, stream>>>(
      xr2, xo2, b_rel2, cnt, eid2, pool2_w, norms + 1, h2, sc2);

  // ---- TopK2 + head ----
  topk2_head_kernel<<<dim3(NG), dim3(K1), 0, stream>>>(h2, sc2, x1p,
      lin1_w, lin1_b, bng, bnb, bnm, bnv, lin2_w, lin2_b, pool1_w, out);
}

// Round 20
// 154.844 us; speedup vs baseline: 1.1695x; 1.1695x over previous
//
#include <hip/hip_runtime.h>
#include <cmath>

// Problem constants
#define NG    128       // graphs
#define NPER  512       // nodes per graph (layer 1)
#define NTOT  65536     // total nodes
#define NEDGE 1048576   // total edges
#define EPG   8192      // edges per graph
#define DD    128
#define K1    256       // kept nodes per graph after pool1
#define K2    128       // kept nodes per graph after pool2
#define SLOTS 56        // fixed edge-bucket slots per node (max degree ~40)

typedef float f32x4 __attribute__((ext_vector_type(4)));
typedef short short8 __attribute__((ext_vector_type(8)));

// 16B-chunk swizzle within a 64B row (shorts offset): conflict-free LDS
__device__ __forceinline__ int SW(int row, int c) { return (c ^ ((row >> 1) & 3)) * 8; }

__device__ __forceinline__ void bsplit(float v, short& h, short& l) {
  unsigned u = __builtin_bit_cast(unsigned, v);
  h = (short)(u >> 16);
  float lf = v - __builtin_bit_cast(float, u & 0xFFFF0000u);
  l = (short)(__builtin_bit_cast(unsigned, lf) >> 16);
}

// async global -> LDS, 16 bytes per lane (lane-linear dest)
__device__ __forceinline__ void gload16(const void* g, void* l) {
  __builtin_amdgcn_global_load_lds(
      (const __attribute__((address_space(1))) unsigned int*)g,
      (__attribute__((address_space(3))) unsigned int*)l, 16, 0, 0);
}

// ---------------------------------------------------------------------------
// Prep: split weights into bf16 hi/lo, MFMA-fragment-ordered layout.
// Also zero cnt and compute ||pool1_w||, ||pool2_w|| into norms[0..1].
// ---------------------------------------------------------------------------
__global__ __launch_bounds__(256) void build_wt_all(
    const float* __restrict__ W1, const float* __restrict__ W2,
    const float* __restrict__ W3, const float* __restrict__ W4,
    const float* __restrict__ pw1, const float* __restrict__ pw2,
    short* __restrict__ h1, short* __restrict__ l1,
    short* __restrict__ h2, short* __restrict__ l2,
    int* __restrict__ cnt, float* __restrict__ norms) {
  const int n = blockIdx.x, k = threadIdx.x;   // n: out-col 0..255, k: 0..255
  cnt[n * 256 + k] = 0;
  const int t = k >> 5, k5 = k & 31, cq = k5 >> 3, i = k5 & 7;
  const int nhalf = n >> 7, nf = (n >> 4) & 7, l = n & 15;
  const int off = ((((t * 2 + nhalf) * 8 + nf) * 4 + cq) * 16 + l) * 8 + i;
  {
    float w = (nhalf == 0) ? W1[k * 128 + n] : W2[k * 128 + (n - 128)];
    short h, lo; bsplit(w, h, lo);
    h1[off] = h; l1[off] = lo;
  }
  if (k < 128) {
    float w = (nhalf == 0) ? W3[k * 128 + n] : W4[k * 128 + (n - 128)];
    short h, lo; bsplit(w, h, lo);
    h2[off] = h; l2[off] = lo;
  }
  if (n == 0) {
    const int lane = k & 63, wid = k >> 6;
    if (wid < 2 && lane < 32) {
      const float* pw = (wid == 0) ? pw1 : pw2;
      f32x4 wv = *(const f32x4*)&pw[lane * 4];
      float nr = wv[0]*wv[0] + wv[1]*wv[1] + wv[2]*wv[2] + wv[3]*wv[3];
#pragma unroll
      for (int m = 16; m >= 1; m >>= 1) nr += __shfl_xor(nr, m);
      if (lane == 0) norms[wid] = sqrtf(nr);
    }
  }
}

// ---------------------------------------------------------------------------
// Split-bf16 MFMA dual GEMM + edge-bucket fill PIPELINED through the K-loop.
// A [M,K] f32 -> C1 = A@W1, C2 = A@W2 (both f32). Tile MT x 256N, 4 waves.
// W double-buffered in LDS via global_load_lds, staged BEFORE compute so the
// barrier's vmcnt(0) drain is covered by MFMA.
// Fill: prologue loads 8 edges/thread (independent coalesced chains, no
// atomics); each K-tile performs 8/NT atomic+store fills issued just before
// the MFMA cluster so the atomic round-trip hides under compute.
// Grid must be 512 blocks. eid must NOT alias any buffer this kernel touches.
// ---------------------------------------------------------------------------
template<int K, int MT, bool FILL2>
__global__ __launch_bounds__(256, 2) void gemm_fill(
    const float* __restrict__ A,
    const short* __restrict__ wth, const short* __restrict__ wtl,
    float* __restrict__ C1, float* __restrict__ C2,
    const int* __restrict__ esrc, const int* __restrict__ edst,
    const int* __restrict__ map, int* __restrict__ cnt, int* __restrict__ eid) {
  constexpr int MF = MT / 32;          // 16-row frags per wave
  constexpr int NP = MT / 32;          // float4s staged per thread
  constexpr int NT = K / 32;
  constexpr int EPT = 8 / NT;          // fill edges per K-tile (1 or 2)
  __shared__ short Ah[MT * 32], Al[MT * 32];
  __shared__ short WHL[2][16384];      // [buf][hi 8192 | lo 8192]
  const int tid = threadIdx.x, lane = tid & 63, wid = tid >> 6;

  const int wm = (wid >> 1) * (MT / 2);
  const int nhalf = wid & 1;           // 0 -> C1, 1 -> C2
  const size_t row0 = (size_t)blockIdx.x * MT;
  const int l15 = lane & 15, cq = lane >> 4;
  const int wfrag = nhalf * 4096 + cq * 128 + l15 * 8;   // B-frag base (shorts)
  const int ar  = (MT == 128) ? (tid >> 1) : (tid >> 2);
  const int cb0 = (MT == 128) ? ((tid & 1) * 2) : (tid & 3);
  const float* ap = A + (row0 + ar) * K + cb0 * 8;

  float4 pa[NP];
  auto load_a = [&](int t) {
    const float4* p = (const float4*)(ap + t * 32);
#pragma unroll
    for (int i = 0; i < NP; ++i) pa[i] = p[i];
  };
  auto store_a = [&]() {
#pragma unroll
    for (int c = 0; c < NP / 2; ++c) {   // per pair of float4s = 8 floats
      float ff[8] = {pa[2*c].x, pa[2*c].y, pa[2*c].z, pa[2*c].w,
                     pa[2*c+1].x, pa[2*c+1].y, pa[2*c+1].z, pa[2*c+1].w};
      short8 hv, lv;
#pragma unroll
      for (int i = 0; i < 8; ++i) {
        short hh, ll; bsplit(ff[i], hh, ll); hv[i] = hh; lv[i] = ll;
      }
      *(short8*)&Ah[ar * 32 + SW(ar, cb0 + c)] = hv;
      *(short8*)&Al[ar * 32 + SW(ar, cb0 + c)] = lv;
    }
  };
  auto stage_w = [&](int t, int b) {
#pragma unroll
    for (int j = 0; j < 8; ++j) {
      int c = wid * 8 + j;
      const short* gs = (c < 16) ? wth + (size_t)t * 8192 + c * 512 + lane * 8
                                 : wtl + (size_t)t * 8192 + (c - 16) * 512 + lane * 8;
      gload16(gs, &WHL[b][c * 512 + lane * 8]);
    }
  };

  f32x4 acc[MF][8];
#pragma unroll
  for (int mf = 0; mf < MF; ++mf)
#pragma unroll
    for (int nf = 0; nf < 8; ++nf) acc[mf][nf] = (f32x4){0.f, 0.f, 0.f, 0.f};

  // prologue: issue GEMM staging first, then edge loads (all independent)
  load_a(0);
  stage_w(0, 0);
  int fsrc[8], fdst[8];
#pragma unroll
  for (int i = 0; i < 8; ++i) {
    int e = blockIdx.x * 2048 + i * 256 + tid;
    if (!FILL2) {
      fsrc[i] = esrc[e];
      fdst[i] = edst[e];
    } else {
      fsrc[i] = map[esrc[e]];
      fdst[i] = map[edst[e]];
    }
  }
  store_a();
  __syncthreads();                    // drains W(0) gloads + A(0) ds_writes
  int cur = 0;

  for (int t = 0; t < NT; ++t) {
    if (t + 1 < NT) {
      load_a(t + 1);                  // global -> regs, lands during compute
      stage_w(t + 1, cur ^ 1);        // async -> other W buffer
    }
    // fill: EPT edges this tile; atomic latency hides under the MFMA cluster
#pragma unroll
    for (int q = 0; q < EPT; ++q) {
      int i = t * EPT + q;
      int s = fsrc[i], d = fdst[i];
      if (!FILL2 || (s | d) >= 0) {
        int pos = atomicAdd(&cnt[d], 1);
        eid[d * SLOTS + pos] = s;
      }
    }
    // compute tile t
    short8 ah[MF], al[MF];
#pragma unroll
    for (int mf = 0; mf < MF; ++mf) {
      int r = wm + mf * 16 + l15;
      ah[mf] = *(const short8*)&Ah[r * 32 + SW(r, cq)];
      al[mf] = *(const short8*)&Al[r * 32 + SW(r, cq)];
    }
#pragma unroll
    for (int nf = 0; nf < 8; ++nf) {
      short8 bh = *(const short8*)&WHL[cur][nf * 512 + wfrag];
      short8 bl = *(const short8*)&WHL[cur][8192 + nf * 512 + wfrag];
#pragma unroll
      for (int mf = 0; mf < MF; ++mf) {
        acc[mf][nf] = __builtin_amdgcn_mfma_f32_16x16x32_bf16(ah[mf], bh, acc[mf][nf], 0, 0, 0);
        acc[mf][nf] = __builtin_amdgcn_mfma_f32_16x16x32_bf16(ah[mf], bl, acc[mf][nf], 0, 0, 0);
        acc[mf][nf] = __builtin_amdgcn_mfma_f32_16x16x32_bf16(al[mf], bh, acc[mf][nf], 0, 0, 0);
      }
    }
    if (t + 1 < NT) {
      __syncthreads();                // ends reads of A(t)/W(t); drain covered by compute
      store_a();                      // A(t+1) -> LDS (single buffer, safe now)
      __syncthreads();                // ds_writes visible
      cur ^= 1;
    }
  }

  float* Cb = nhalf ? C2 : C1;
#pragma unroll
  for (int mf = 0; mf < MF; ++mf) {
    size_t rbase = row0 + wm + mf * 16 + cq * 4;
#pragma unroll
    for (int nf = 0; nf < 8; ++nf) {
      int c = nf * 16 + l15;
#pragma unroll
      for (int r = 0; r < 4; ++r)
        Cb[(rbase + r) * 128 + c] = acc[mf][nf][r];
    }
  }
}

// ---------------------------------------------------------------------------
// Gather aggregation: ONE WAVE PER BLOCK (64 threads) -> zero intra-block
// wave imbalance. Whole bucket in one coalesced load; 4 chains, 2 edges per
// f32x4 load; ||w|| precomputed. Fused TopK score. XCD-swizzled blocks.
// ---------------------------------------------------------------------------
template<int CPX>
__global__ __launch_bounds__(64) void agg_gather(
    const float* __restrict__ xr, const float* __restrict__ xo,
    const float* __restrict__ brel, const int* __restrict__ cnt,
    const int* __restrict__ eid, const float* __restrict__ pw,
    const float* __restrict__ wnorm_p,
    float* __restrict__ hout, float* __restrict__ score) {
  const int bid = blockIdx.x;
  const int node = (bid & 7) * CPX + (bid >> 3);   // XCD swizzle
  const int lane = threadIdx.x;
  const int dg = cnt[node];           // wave-uniform
  const int base = node * SLOTS;
  const int half = lane >> 5, l32 = lane & 31;
  const int eall = eid[base + lane];  // whole bucket, one coalesced load
  const float wnorm = wnorm_p[0];     // uniform scalar
  f32x4 a0 = {0.f, 0.f, 0.f, 0.f}, a1 = a0, a2 = a0, a3 = a0;
  int j = 0;
  for (; j + 8 <= dg; j += 8) {       // uniform branch
    int e0 = __shfl(eall, j + 0 + half);
    int e1 = __shfl(eall, j + 2 + half);
    int e2 = __shfl(eall, j + 4 + half);
    int e3 = __shfl(eall, j + 6 + half);
    a0 += *(const f32x4*)&xr[(size_t)e0 * 128 + l32 * 4];
    a1 += *(const f32x4*)&xr[(size_t)e1 * 128 + l32 * 4];
    a2 += *(const f32x4*)&xr[(size_t)e2 * 128 + l32 * 4];
    a3 += *(const f32x4*)&xr[(size_t)e3 * 128 + l32 * 4];
  }
  if (j + 4 <= dg) {
    int e0 = __shfl(eall, j + 0 + half);
    int e1 = __shfl(eall, j + 2 + half);
    a0 += *(const f32x4*)&xr[(size_t)e0 * 128 + l32 * 4];
    a1 += *(const f32x4*)&xr[(size_t)e1 * 128 + l32 * 4];
    j += 4;
  }
  if (j + 2 <= dg) {
    int e0 = __shfl(eall, j + half);
    a2 += *(const f32x4*)&xr[(size_t)e0 * 128 + l32 * 4];
    j += 2;
  }
  {
    int e0 = __shfl(eall, j);
    if (j < dg && half == 0)
      a3 += *(const f32x4*)&xr[(size_t)e0 * 128 + l32 * 4];
  }
  f32x4 s = a0 + a1 + a2 + a3;
  s[0] += __shfl_xor(s[0], 32);
  s[1] += __shfl_xor(s[1], 32);
  s[2] += __shfl_xor(s[2], 32);
  s[3] += __shfl_xor(s[3], 32);
  float dot = 0.f;
  if (half == 0) {
    const f32x4 wv = *(const f32x4*)&pw[l32 * 4];
    f32x4 b = *(const f32x4*)&brel[l32 * 4];
    f32x4 o = *(const f32x4*)&xo[(size_t)node * 128 + l32 * 4];
    f32x4 h;
#pragma unroll
    for (int i = 0; i < 4; ++i) {
      h[i] = fmaxf(s[i] + b[i] + o[i], 0.f);
      dot += h[i] * wv[i];
    }
    *(f32x4*)&hout[(size_t)node * 128 + l32 * 4] = h;
  }
#pragma unroll
  for (int m = 16; m >= 1; m >>= 1) dot += __shfl_xor(dot, m);
  if (lane == 0)
    score[node] = 1.f / (1.f + expf(-dot / wnorm));
}

// ---------------------------------------------------------------------------
// TopK pool 1 (512 -> 256 per graph): scores precomputed by agg_gather.
// Also zeroes cnt for layer 2.
// ---------------------------------------------------------------------------
__global__ __launch_bounds__(512) void topk1_kernel(
    const float* __restrict__ h1, const float* __restrict__ score_in,
    float* __restrict__ xnew, int* __restrict__ map, int* __restrict__ cnt,
    float* __restrict__ x1p, float* __restrict__ score_out) {
  const int g = blockIdx.x, tid = threadIdx.x;
  __shared__ float sc[NPER];
  __shared__ int si[NPER];
  __shared__ float xn[K1 * 128];
  __shared__ float redm[4 * 128];
  __shared__ float reds[4 * 128];
  {
    int gt = g * 512 + tid;
    if (gt < NG * K1) cnt[gt] = 0;   // zero layer-2 buckets
  }
  sc[tid] = score_in[g * NPER + tid];
  si[tid] = tid;

  // bitonic sort, descending score, ties -> lower index first (lax.top_k)
  for (int k = 2; k <= NPER; k <<= 1) {
    for (int j = k >> 1; j > 0; j >>= 1) {
      __syncthreads();
      int p = tid ^ j;
      if (p > tid) {
        float sa = sc[tid], sb = sc[p];
        int ia = si[tid], ib = si[p];
        bool before = (sb > sa) || (sb == sa && ib < ia);
        if (before == ((tid & k) == 0)) {
          sc[tid] = sb; sc[p] = sa; si[tid] = ib; si[p] = ia;
        }
      }
    }
  }
  __syncthreads();

  map[g * NPER + tid] = -1;
  if (tid < K1) score_out[g * K1 + tid] = sc[tid];
  __syncthreads();
  if (tid < K1) map[g * NPER + si[tid]] = g * K1 + tid;

  const int wave = tid >> 6, lane = tid & 63;
  for (int j = wave; j < K1; j += 8) {
    int idx = si[j];
    float s2 = sc[j];
    float2 v = *(const float2*)&h1[(size_t)(g * NPER + idx) * 128 + lane * 2];
    float2 o;
    o.x = v.x * s2;
    o.y = v.y * s2;
    *(float2*)&xnew[(size_t)(g * K1 + j) * 128 + lane * 2] = o;
    xn[j * 128 + lane * 2] = o.x;
    xn[j * 128 + lane * 2 + 1] = o.y;
  }
  __syncthreads();

  const int c = tid & 127, grp = tid >> 7;   // 4 groups
  float mx = -1e30f, sm = 0.f;
  for (int r = grp; r < K1; r += 4) {
    float v = xn[r * 128 + c];
    mx = fmaxf(mx, v);
    sm += v;
  }
  redm[grp * 128 + c] = mx;
  reds[grp * 128 + c] = sm;
  __syncthreads();
  if (tid < 128) {
    float m = fmaxf(fmaxf(redm[c], redm[128 + c]), fmaxf(redm[256 + c], redm[384 + c]));
    float su = reds[c] + reds[128 + c] + reds[256 + c] + reds[384 + c];
    x1p[g * 256 + tid] = m;
    x1p[g * 256 + 128 + tid] = su * (1.f / 256.f);
  }
}

// ---------------------------------------------------------------------------
// TopK pool 2 (256 -> 128, scores precomputed) fused with classifier head.
// ---------------------------------------------------------------------------
__global__ __launch_bounds__(256) void topk2_head_kernel(
    const float* __restrict__ h2, const float* __restrict__ score_in,
    const float* __restrict__ x1p,
    const float* __restrict__ lin1_w, const float* __restrict__ lin1_b,
    const float* __restrict__ bng, const float* __restrict__ bnb,
    const float* __restrict__ bnm, const float* __restrict__ bnv,
    const float* __restrict__ lin2_w, const float* __restrict__ lin2_b,
    const float* __restrict__ pool1_w, float* __restrict__ out) {
  const int g = blockIdx.x, tid = threadIdx.x;
  __shared__ float sc[K1];
  __shared__ int si[K1];
  __shared__ float xn[K2 * 128];
  __shared__ float redm[2 * 128];
  __shared__ float reds[2 * 128];
  __shared__ float ge[256];
  __shared__ float zz[128];
  __shared__ float lg[16];
  sc[tid] = score_in[g * K1 + tid];
  si[tid] = tid;
  for (int k = 2; k <= K1; k <<= 1) {
    for (int j = k >> 1; j > 0; j >>= 1) {
      __syncthreads();
      int p = tid ^ j;
      if (p > tid) {
        float sa = sc[tid], sb = sc[p];
        int ia = si[tid], ib = si[p];
        bool before = (sb > sa) || (sb == sa && ib < ia);
        if (before == ((tid & k) == 0)) {
          sc[tid] = sb; sc[p] = sa; si[tid] = ib; si[p] = ia;
        }
      }
    }
  }
  __syncthreads();
  const int wave = tid >> 6, lane = tid & 63;  // 4 waves
  for (int j = wave; j < K2; j += 4) {
    int idx = si[j];
    float s2 = sc[j];
    float2 v = *(const float2*)&h2[(size_t)(g * K1 + idx) * 128 + lane * 2];
    xn[j * 128 + lane * 2] = v.x * s2;
    xn[j * 128 + lane * 2 + 1] = v.y * s2;
  }
  __syncthreads();
  const int c = tid & 127, grp = tid >> 7;  // 2 groups
  float mx = -1e30f, sm = 0.f;
  for (int r = grp; r < K2; r += 2) {
    float v = xn[r * 128 + c];
    mx = fmaxf(mx, v);
    sm += v;
  }
  redm[grp * 128 + c] = mx;
  reds[grp * 128 + c] = sm;
  __syncthreads();
  // ---- head ----
  if (tid < 128) {
    float m = fmaxf(redm[c], redm[128 + c]);
    float su = (reds[c] + reds[128 + c]) * (1.f / 128.f);
    float v1 = x1p[g * 256 + tid] + m;
    float v2 = x1p[g * 256 + 128 + tid] + su;
    ge[tid] = v1;
    ge[128 + tid] = v2;
    out[2048 + g * 256 + tid] = v1;          // g_emb output
    out[2048 + g * 256 + 128 + tid] = v2;
  }
  __syncthreads();
  if (tid < 128) {
    float a = lin1_b[tid];
    for (int k = 0; k < 256; ++k) a += ge[k] * lin1_w[k * 128 + tid];
    a = fmaxf(a, 0.f);
    a = (a - bnm[tid]) * bng[tid] / sqrtf(bnv[tid] + 1e-5f) + bnb[tid];
    zz[tid] = a;
  }
  __syncthreads();
  if (tid < 16) {
    float o = lin2_b[tid];
    for (int k = 0; k < 128; ++k) o += zz[k] * lin2_w[k * 16 + tid];
    lg[tid] = o;
  }
  __syncthreads();
  if (tid < 16) {
    float m = lg[0];
    for (int j = 1; j < 16; ++j) m = fmaxf(m, lg[j]);
    float ssum = 0.f;
    for (int j = 0; j < 16; ++j) ssum += expf(lg[j] - m);
    out[g * 16 + tid] = lg[tid] - m - logf(ssum);
  }
  if (g == 0 && tid < 128) out[34816 + tid] = pool1_w[tid];  // pool1_w output
}

// ---------------------------------------------------------------------------
extern "C" void kernel_launch(void* const* d_in, const int* in_sizes, int n_in,
                              void* d_out, int out_size, void* d_ws, size_t ws_size,
                              hipStream_t stream) {
  const float* x       = (const float*)d_in[0];
  const int*   ei      = (const int*)d_in[1];
  const float* w_rel1  = (const float*)d_in[3];
  const float* b_rel1  = (const float*)d_in[4];
  const float* w_root1 = (const float*)d_in[5];
  const float* pool1_w = (const float*)d_in[6];
  const float* w_rel2  = (const float*)d_in[7];
  const float* b_rel2  = (const float*)d_in[8];
  const float* w_root2 = (const float*)d_in[9];
  const float* pool2_w = (const float*)d_in[10];
  const float* lin1_w  = (const float*)d_in[11];
  const float* lin1_b  = (const float*)d_in[12];
  const float* bng     = (const float*)d_in[13];
  const float* bnb     = (const float*)d_in[14];
  const float* bnm     = (const float*)d_in[15];
  const float* bnv     = (const float*)d_in[16];
  const float* lin2_w  = (const float*)d_in[17];
  const float* lin2_b  = (const float*)d_in[18];
  const int* src = ei;
  const int* dst = ei + NEDGE;

  char* ws = (char*)d_ws;
  // Memory map (bytes):
  //  [0,16M)      xr2 (layer2)        ; layer1: xr1 lower half
  //  [0,32M)      xr1 [65536][128]
  //  [16M,32M)    xo2 (layer2)
  //  [32M,48M)    xoh1/h1 lower half  ; layer2: h2
  //  [48M,~55.3M) eid2 (dead h1 upper half during gemm2/agg2)
  //  [32M,64M)    xoh1/h1 (layer1)
  //  [64M,~78.7M) eid1 (during gemm1/agg1) -> xnew [64M,80M) after topk1
  //  [80M,..)     map, cnt, x1p, sc1, sc2, wth/wtl, norms
  float* xr1  = (float*)(ws + 0);
  float* xoh1 = (float*)(ws + 33554432UL);
  float* xnew = (float*)(ws + 67108864UL);
  int*   eid1 = (int*)  (ws + 67108864UL);
  int*   eid2 = (int*)  (ws + 50331648UL);
  int*   map  = (int*)  (ws + 83886080UL);
  int*   cnt  = (int*)  (ws + 84148224UL);
  float* x1p  = (float*)(ws + 84410368UL);
  float* sc1  = (float*)(ws + 84541440UL);
  float* sc2  = (float*)(ws + 84803584UL);
  short* wth1 = (short*)(ws + 84934656UL);
  short* wtl1 = (short*)(ws + 85065728UL);
  short* wth2 = (short*)(ws + 85196800UL);
  short* wtl2 = (short*)(ws + 85262336UL);
  float* norms = (float*)(ws + 85327872UL);
  float* xr2  = (float*)(ws + 0);
  float* xo2  = (float*)(ws + 16777216UL);
  float* h2   = xoh1;
  float* out  = (float*)d_out;

  // ---- Layer 1 ----
  build_wt_all<<<dim3(256), dim3(256), 0, stream>>>(
      w_rel1, w_root1, w_rel2, w_root2, pool1_w, pool2_w,
      wth1, wtl1, wth2, wtl2, cnt, norms);
  gemm_fill<256, 128, false><<<dim3(512), dim3(256), 0, stream>>>(
      x, wth1, wtl1, xr1, xoh1, src, dst, nullptr, cnt, eid1);
  agg_gather<8192><<<dim3(NTOT), dim3(64), 0, stream>>>(
      xr1, xoh1, b_rel1, cnt, eid1, pool1_w, norms, xoh1, sc1);
  topk1_kernel<<<dim3(NG), dim3(512), 0, stream>>>(xoh1, sc1, xnew, map, cnt, x1p, out + 34944);

  // ---- Layer 2 ----
  gemm_fill<128, 64, true><<<dim3(512), dim3(256), 0, stream>>>(
      xnew, wth2, wtl2, xr2, xo2, src, dst, map, cnt, eid2);
  agg_gather<4096><<<dim3(NG * K1), dim3(64), 0, stream>>>(
      xr2, xo2, b_rel2, cnt, eid2, pool2_w, norms + 1, h2, sc2);

  // ---- TopK2 + head ----
  topk2_head_kernel<<<dim3(NG), dim3(K1), 0, stream>>>(h2, sc2, x1p,
      lin1_w, lin1_b, bng, bnb, bnm, bnv, lin2_w, lin2_b, pool1_w, out);
}